// Round 12
// baseline (176.374 us; speedup 1.0000x reference)
//
#include <hip/hip_runtime.h>

#define D 128
#define BN_EPS 1e-5f
#define K_ELL 40
#define NB_AGG 2048
#define NB_FILL 1024

typedef __attribute__((ext_vector_type(8))) short bf16x8;
typedef __attribute__((ext_vector_type(4))) float f32x4;

__device__ __forceinline__ unsigned bf16rne(float f) {
    unsigned u = __float_as_uint(f);
    return (u + 0x7fffu + ((u >> 16) & 1u)) >> 16;
}
__device__ __forceinline__ float bflo(unsigned p) { return __uint_as_float(p << 16); }
__device__ __forceinline__ float bfhi(unsigned p) { return __uint_as_float(p & 0xffff0000u); }

// ============ fused: gemm (blocks < gemm_nb) + degree/ELL fill (rest) ============
// gemm LDS: x tile only (17.4 KB). W fragments live in registers, loaded from
// fp32 W in global (L2-resident 64 KB) -> no per-block transpose, no wsb conflicts.
__global__ __launch_bounds__(256) void gemm_fill(
    const float* __restrict__ x, const float* __restrict__ W,
    const int* __restrict__ prow, const int* __restrict__ pcol,
    int* __restrict__ deg, int* __restrict__ ell,
    int2* __restrict__ ovf, int* __restrict__ ovf_cnt,
    ushort* __restrict__ hb, int n, int E, int gemm_nb)
{
    __shared__ ushort xsb[64][136];   // [row][k], pad -> free 2-way banks
    int tid = threadIdx.x;

    if (blockIdx.x >= gemm_nb) {
        // ---- fill role: one-pass degree count + ELL ----
        int gtid = (blockIdx.x - gemm_nb) * 256 + tid;
        for (int e = gtid; e < E; e += NB_FILL * 256) {
            int c = pcol[e];
            int r = prow[e];
            int p = atomicAdd(&deg[c], 1);
            if (p < K_ELL) {
                ell[c * K_ELL + p] = r;
            } else {  // statistically never at deg~Poisson(10)
                int q = atomicAdd(ovf_cnt, 1);
                ovf[q] = make_int2(c, r);
            }
        }
        return;
    }

    // ---- gemm role: h = bf16(x) @ bf16(W) via MFMA, bf16 store ----
    int wave = tid >> 6;
    int lane = tid & 63;
    int row0 = blockIdx.x * 64;
    int ar = lane & 15;            // A row / B col within 16-tile
    int ako = (lane >> 4) * 8;     // k offset within K=32 chunk

    // B-fragments in registers: W[k][col] fp32 -> bf16, col = wave*32+nt*16+ar
    // 16-lane groups read 64B contiguous; all L2-hits after first blocks.
    bf16x8 bfrag[4][2];
    #pragma unroll
    for (int kk = 0; kk < 4; kk++) {
        #pragma unroll
        for (int nt = 0; nt < 2; nt++) {
            const float* wp = &W[(kk * 32 + ako) * D + wave * 32 + nt * 16 + ar];
            uint bu[4];
            #pragma unroll
            for (int j = 0; j < 4; j++) {
                float f0 = wp[(2 * j) * D];
                float f1 = wp[(2 * j + 1) * D];
                bu[j] = bf16rne(f0) | (bf16rne(f1) << 16);
            }
            bfrag[kk][nt] = *(bf16x8*)bu;
        }
    }

    // stage x tile fp32 -> bf16 into LDS (shared by all 4 waves)
    {
        int r = tid >> 2, kq = tid & 3;
        int grow = row0 + r;
        if (grow >= n) grow = n - 1;
        const float4* src = (const float4*)&x[(size_t)grow * D + kq * 32];
        uint* dst = (uint*)&xsb[r][kq * 32];
        #pragma unroll
        for (int q = 0; q < 8; q++) {
            float4 v = src[q];
            dst[q * 2]     = bf16rne(v.x) | (bf16rne(v.y) << 16);
            dst[q * 2 + 1] = bf16rne(v.z) | (bf16rne(v.w) << 16);
        }
    }
    __syncthreads();

    f32x4 acc[4][2];
    #pragma unroll
    for (int mt = 0; mt < 4; mt++)
        #pragma unroll
        for (int nt = 0; nt < 2; nt++)
            acc[mt][nt] = (f32x4){0.f, 0.f, 0.f, 0.f};

    #pragma unroll
    for (int kk = 0; kk < 4; kk++) {
        bf16x8 a[4];
        #pragma unroll
        for (int mt = 0; mt < 4; mt++)
            a[mt] = *(const bf16x8*)&xsb[mt * 16 + ar][kk * 32 + ako];
        #pragma unroll
        for (int mt = 0; mt < 4; mt++)
            #pragma unroll
            for (int nt = 0; nt < 2; nt++)
                acc[mt][nt] = __builtin_amdgcn_mfma_f32_16x16x32_bf16(
                    a[mt], bfrag[kk][nt], acc[mt][nt], 0, 0, 0);
    }

    int col = lane & 15, rq = (lane >> 4) * 4;
    #pragma unroll
    for (int mt = 0; mt < 4; mt++) {
        #pragma unroll
        for (int r = 0; r < 4; r++) {
            int grow = row0 + mt * 16 + rq + r;
            if (grow < n) {
                #pragma unroll
                for (int nt = 0; nt < 2; nt++)
                    hb[(size_t)grow * D + wave * 32 + nt * 16 + col] =
                        (ushort)bf16rne(acc[mt][nt][r]);
            }
        }
    }
}

// ---------------- aggregation: wave/node, ELL gather, unroll-4, partials out ----------------
__global__ __launch_bounds__(512) void aggregate(const unsigned* __restrict__ hb,
                                                 const int* __restrict__ deg,
                                                 const int* __restrict__ ell,
                                                 const int2* __restrict__ ovf,
                                                 const int* __restrict__ ovf_cnt,
                                                 const float* __restrict__ bias,
                                                 float* __restrict__ out,
                                                 float* __restrict__ partials, int n) {
    int tid = threadIdx.x;
    int wave = tid >> 6;      // 0..7
    int lane = tid & 63;
    float2 bv = *(const float2*)&bias[lane * 2];
    float s1a = 0.f, s1b = 0.f, s2a = 0.f, s2b = 0.f;

    for (int node = blockIdx.x * 8 + wave; node < n; node += gridDim.x * 8) {
        int cntT = deg[node];
        float dc = rsqrtf((float)cntT + 1.0f);
        int cntE = cntT < K_ELL ? cntT : K_ELL;
        unsigned hp = hb[(size_t)node * 64 + lane];
        float ax = dc * bflo(hp), ay = dc * bfhi(hp);
        int es = (lane < cntE) ? ell[node * K_ELL + lane] : 0;
        float ed = (lane < cntE) ? rsqrtf((float)deg[es] + 1.0f) : 0.f;
        int e = 0;
        for (; e + 4 <= cntE; e += 4) {
            int sA = __shfl(es, e), sB = __shfl(es, e + 1);
            int sC = __shfl(es, e + 2), sD = __shfl(es, e + 3);
            float dA = __shfl(ed, e), dB = __shfl(ed, e + 1);
            float dC = __shfl(ed, e + 2), dD = __shfl(ed, e + 3);
            unsigned hA = hb[(size_t)sA * 64 + lane];
            unsigned hB = hb[(size_t)sB * 64 + lane];
            unsigned hC = hb[(size_t)sC * 64 + lane];
            unsigned hD = hb[(size_t)sD * 64 + lane];
            ax += dA * bflo(hA); ay += dA * bfhi(hA);
            ax += dB * bflo(hB); ay += dB * bfhi(hB);
            ax += dC * bflo(hC); ay += dC * bfhi(hC);
            ax += dD * bflo(hD); ay += dD * bfhi(hD);
        }
        for (; e < cntE; e++) {
            int s = __shfl(es, e);
            float dv = __shfl(ed, e);
            unsigned hq = hb[(size_t)s * 64 + lane];
            ax += dv * bflo(hq); ay += dv * bfhi(hq);
        }
        if (cntT > K_ELL) {  // overflow scan (practically never taken)
            int novf = *ovf_cnt;
            for (int j = 0; j < novf; j++) {
                int2 q = ovf[j];
                if (q.x == node) {
                    float dv = rsqrtf((float)deg[q.y] + 1.0f);
                    unsigned hq = hb[(size_t)q.y * 64 + lane];
                    ax += dv * bflo(hq); ay += dv * bfhi(hq);
                }
            }
        }
        float ox = dc * ax + bv.x;
        float oy = dc * ay + bv.y;
        *(float2*)&out[(size_t)node * D + lane * 2] = make_float2(ox, oy);
        s1a += ox; s1b += oy;
        s2a += ox * ox; s2b += oy * oy;
    }

    // 8-wave LDS reduce, one coalesced 1 KB partial write per block (no atomics)
    __shared__ float l1[8][128], l2[8][128];
    l1[wave][lane * 2] = s1a; l1[wave][lane * 2 + 1] = s1b;
    l2[wave][lane * 2] = s2a; l2[wave][lane * 2 + 1] = s2b;
    __syncthreads();
    if (tid < 256) {
        int col = tid & 127;
        float v;
        if (tid < 128) {
            v = l1[0][col] + l1[1][col] + l1[2][col] + l1[3][col] +
                l1[4][col] + l1[5][col] + l1[6][col] + l1[7][col];
        } else {
            v = l2[0][col] + l2[1][col] + l2[2][col] + l2[3][col] +
                l2[4][col] + l2[5][col] + l2[6][col] + l2[7][col];
        }
        partials[(size_t)blockIdx.x * 256 + tid] = v;
    }
}

// ---------------- fold partials [NB_AGG][256] into gsum/gsumsq (parallel) ----------------
__global__ __launch_bounds__(256) void bn_reduce(const float* __restrict__ partials,
                                                 float* __restrict__ gsum,
                                                 float* __restrict__ gsumsq, int nrows) {
    int tid = threadIdx.x;
    float s = 0.f;
    for (int r = blockIdx.x; r < nrows; r += gridDim.x)
        s += partials[(size_t)r * 256 + tid];
    if (tid < 128) atomicAdd(&gsum[tid], s);
    else           atomicAdd(&gsumsq[tid - 128], s);
}

// ---------------- BN finalize + ReLU (in place, float4) ----------------
__global__ __launch_bounds__(256) void bn_finalize(float4* __restrict__ out4,
                                                   const float* __restrict__ gsum,
                                                   const float* __restrict__ gsumsq,
                                                   const float* __restrict__ gamma,
                                                   const float* __restrict__ beta,
                                                   int total4, float invN) {
    int i0 = blockIdx.x * 256 + threadIdx.x;
    int c = (i0 * 4) & 127;  // grid stride in floats is a multiple of 128
    float4 g4 = *(const float4*)&gsum[c];
    float4 q4 = *(const float4*)&gsumsq[c];
    float4 gm = *(const float4*)&gamma[c];
    float4 bt = *(const float4*)&beta[c];
    float m0 = g4.x * invN, m1 = g4.y * invN, m2 = g4.z * invN, m3 = g4.w * invN;
    float sc0 = rsqrtf(q4.x * invN - m0 * m0 + BN_EPS) * gm.x;
    float sc1 = rsqrtf(q4.y * invN - m1 * m1 + BN_EPS) * gm.y;
    float sc2 = rsqrtf(q4.z * invN - m2 * m2 + BN_EPS) * gm.z;
    float sc3 = rsqrtf(q4.w * invN - m3 * m3 + BN_EPS) * gm.w;
    float sh0 = bt.x - m0 * sc0, sh1 = bt.y - m1 * sc1;
    float sh2 = bt.z - m2 * sc2, sh3 = bt.w - m3 * sc3;
    for (int i = i0; i < total4; i += gridDim.x * 256) {
        float4 v = out4[i];
        v.x = fmaxf(fmaf(v.x, sc0, sh0), 0.f);
        v.y = fmaxf(fmaf(v.y, sc1, sh1), 0.f);
        v.z = fmaxf(fmaf(v.z, sc2, sh2), 0.f);
        v.w = fmaxf(fmaf(v.w, sc3, sh3), 0.f);
        out4[i] = v;
    }
}

extern "C" void kernel_launch(void* const* d_in, const int* in_sizes, int n_in,
                              void* d_out, int out_size, void* d_ws, size_t ws_size,
                              hipStream_t stream) {
    const float* x     = (const float*)d_in[0];
    const int*   pos   = (const int*)d_in[1];
    const float* W     = (const float*)d_in[3];
    const float* bias  = (const float*)d_in[4];
    const float* gamma = (const float*)d_in[5];
    const float* beta  = (const float*)d_in[6];
    float* out = (float*)d_out;

    int N  = in_sizes[0] / D;
    int EP = in_sizes[1] / 2;
    const int* prow = pos;
    const int* pcol = pos + EP;
    int gemm_nb = (N + 63) / 64;

    auto align = [](size_t v) { return (v + 255) & ~(size_t)255; };
    char* p = (char*)d_ws;
    // ---- zeroed region (one memset): deg, ovf_cnt, gsum, gsumsq ----
    int*    deg     = (int*)p;    p += align((size_t)N * 4);
    int*    ovf_cnt = (int*)p;    p += align(256);
    float*  gsum    = (float*)p;  p += align((size_t)D * 4);
    float*  gsumsq  = (float*)p;  p += align((size_t)D * 4);
    size_t zbytes = (size_t)(p - (char*)d_ws);
    // ---- rest ----
    int*    ell      = (int*)p;    p += align((size_t)N * K_ELL * 4);
    int2*   ovf      = (int2*)p;   p += align((size_t)EP * 8);
    ushort* hb       = (ushort*)p; p += align((size_t)N * D * 2);
    float*  partials = (float*)p;  p += align((size_t)NB_AGG * 256 * 4);

    hipMemsetAsync(d_ws, 0, zbytes, stream);
    gemm_fill<<<gemm_nb + NB_FILL, 256, 0, stream>>>(x, W, prow, pcol, deg, ell, ovf,
                                                     ovf_cnt, hb, N, EP, gemm_nb);
    aggregate<<<NB_AGG, 512, 0, stream>>>((const unsigned*)hb, deg, ell, ovf, ovf_cnt,
                                          bias, out, partials, N);
    bn_reduce<<<64, 256, 0, stream>>>(partials, gsum, gsumsq, NB_AGG);
    bn_finalize<<<1600, 256, 0, stream>>>((float4*)out, gsum, gsumsq, gamma, beta,
                                          N * D / 4, 1.0f / (float)N);
}